// Round 11
// baseline (77.715 us; speedup 1.0000x reference)
//
#include <hip/hip_runtime.h>
#include <hip/hip_fp16.h>
#include <math.h>

// Siddon forward projection, 128^3 grid over [-1,1]^3, voxel = 1/64.
// ONE WAVE PER RAY, lane-parallel segment enumeration (no serial traversal):
// every Siddon segment starts at a plane crossing (or amin). Lane t handles
// crossing t via an O(1) map t->(axis,plane); its segment ends at the min over
// axes of the next crossing after alpha0 (computed by position + exact-alpha
// fixups; lexicographic (alpha, axis) tie-break avoids double-count/gap on
// bit-exact ties). All 64 lane loads are independent -> full MLP, and lanes
// of one wave share one ray -> zero intra-wave imbalance.
// Image is fp16 in workspace (4 MB -> L2-resident per XCD), proven round 7.

static constexpr float VOX = 0.015625f;   // 2/128, exact power of two
static constexpr float INV_VOX = 64.0f;
static constexpr int   NVOX = 128 * 128 * 128;

// First plane index strictly past amin in walk order, its alpha (exact
// reference expression), and the crossing count in (amin, amax].
__device__ __forceinline__ void axis_init(float amin, float amax, float p0,
                                          float ds, float inv,
                                          int& st, int& ip, float& al, int& cnt) {
  float ts = (fmaf(amin, ds, p0) + 1.0f) * INV_VOX;
  float te = (fmaf(amax, ds, p0) + 1.0f) * INV_VOX;
  if (ds > 0.0f) {
    ip = (int)floorf(ts) + 1;
    int il = (int)floorf(te); if (il > 128) il = 128;
    cnt = il - ip + 1; st = 1;
  } else {
    ip = (int)ceilf(ts) - 1;
    int il = (int)ceilf(te); if (il < 0) il = 0;
    cnt = ip - il + 1; st = -1;
  }
  if (cnt < 0) cnt = 0;
  al = (fmaf((float)ip, VOX, -1.0f) - p0) * inv;
}

// First crossing of axis b after alpha0. strict: alpha > alpha0; else >=.
// Candidate plane from the position at alpha0, then +-1 fixups using the
// EXACT alpha expression (same bits as any lane's own alpha0) so comparisons
// against other lanes' segment starts are consistent.
__device__ __forceinline__ float next_cross(float a0, float pos, float p0b,
                                            float invb, int stb, bool strict) {
  float tt = (pos + 1.0f) * INV_VOX;
  int q = (stb > 0) ? ((int)floorf(tt) + 1) : ((int)ceilf(tt) - 1);
  float ab  = (fmaf((float)q, VOX, -1.0f) - p0b) * invb;
  float abp = (fmaf((float)(q - stb), VOX, -1.0f) - p0b) * invb;
  bool back = strict ? (abp > a0) : (abp >= a0);
  int  q2 = back ? (q - stb) : q;
  ab = back ? abp : ab;
  bool fwd = strict ? (ab <= a0) : (ab < a0);
  float abn = (fmaf((float)(q2 + stb), VOX, -1.0f) - p0b) * invb;
  ab = fwd ? abn : ab;
  return ab;
}

// --- image fp32 -> fp16 (workspace) -----------------------------------------
__global__ __launch_bounds__(256) void convert_h(
    const float* __restrict__ img, __half* __restrict__ h)
{
  int i = blockIdx.x * blockDim.x + threadIdx.x;
  int stride = gridDim.x * blockDim.x;
  for (; i < NVOX; i += stride) h[i] = __float2half(img[i]);
}

// --- projection: one wave per ray --------------------------------------------
__global__ __launch_bounds__(256) void siddon_fp(
    const __half* __restrict__ image,
    const float* __restrict__ lors,
    float* __restrict__ out, int n)
{
  int ray  = (blockIdx.x * blockDim.x + threadIdx.x) >> 6;
  int lane = threadIdx.x & 63;
  if (ray >= n) return;

  const float* L = lors + (long)ray * 6;
  float p0x = L[0], p0y = L[1], p0z = L[2];
  float dx  = L[3] - p0x, dy = L[4] - p0y, dz = L[5] - p0z;

  const float eps = 1e-9f;
  float dsx = (fabsf(dx) < eps) ? eps : dx;
  float dsy = (fabsf(dy) < eps) ? eps : dy;
  float dsz = (fabsf(dz) < eps) ? eps : dz;

  float invx = __builtin_amdgcn_rcpf(dsx);
  float invy = __builtin_amdgcn_rcpf(dsy);
  float invz = __builtin_amdgcn_rcpf(dsz);

  float a0 = (-1.0f - p0x) * invx, a1 = (1.0f - p0x) * invx;
  float axmin = fminf(a0, a1), axmax = fmaxf(a0, a1);
  a0 = (-1.0f - p0y) * invy; a1 = (1.0f - p0y) * invy;
  float aymin = fminf(a0, a1), aymax = fmaxf(a0, a1);
  a0 = (-1.0f - p0z) * invz; a1 = (1.0f - p0z) * invz;
  float azmin = fminf(a0, a1), azmax = fmaxf(a0, a1);

  float amin = fmaxf(fmaxf(axmin, aymin), fmaxf(azmin, 0.0f));
  float amax = fminf(fminf(axmax, aymax), fminf(azmax, 1.0f));

  float acc = 0.0f;
  if (amax > amin) {
    int stx, sty, stz, ipx, ipy, ipz, c0, c1, c2;
    float alx, aly, alz;
    axis_init(amin, amax, p0x, dsx, invx, stx, ipx, alx, c0);
    axis_init(amin, amax, p0y, dsy, invy, sty, ipy, aly, c1);
    axis_init(amin, amax, p0z, dsz, invz, stz, ipz, alz, c2);

    int V = c0 + c1 + c2;            // crossings; +1 segment starting at amin
    int nit = (V + 64) >> 6;         // ceil((V+1)/64), uniform across the wave

    for (int it = 0; it < nit; ++it) {
      int t = (it << 6) + lane;
      // map t -> (axis a, plane p); t==V -> amin segment; t>V -> padding
      bool ge1 = t >= c0, ge2 = t >= (c0 + c1);
      int  a   = (ge1 ? 1 : 0) + (ge2 ? 1 : 0);
      int  tb  = t - (ge2 ? (c0 + c1) : (ge1 ? c0 : 0));
      float p0a  = ge2 ? p0z : (ge1 ? p0y : p0x);
      float inva = ge2 ? invz : (ge1 ? invy : invx);
      int   ipa  = ge2 ? ipz : (ge1 ? ipy : ipx);
      int   sta  = ge2 ? stz : (ge1 ? sty : stx);
      int   p    = ipa + sta * tb;

      float alpha0 = (fmaf((float)p, VOX, -1.0f) - p0a) * inva;
      bool amin_lane = (t == V);
      bool pad       = (t > V);      // pad lanes: a==2 -> all-strict -> dif=0
      alpha0 = amin_lane ? amin : (pad ? amax : alpha0);

      float posx = fmaf(alpha0, dx, p0x);
      float posy = fmaf(alpha0, dy, p0y);
      float posz = fmaf(alpha0, dz, p0z);
      // tie-break: axis b "after" alpha0 is strict for b<=a, non-strict for b>a
      float nx = next_cross(alpha0, posx, p0x, invx, stx, true);
      float ny = next_cross(alpha0, posy, p0y, invy, sty, a >= 1);
      float nz = next_cross(alpha0, posz, p0z, invz, stz, a >= 2);
      nx = amin_lane ? alx : nx;
      ny = amin_lane ? aly : ny;
      nz = amin_lane ? alz : nz;

      float aend = fminf(fminf(nx, ny), fminf(nz, amax));
      float dif  = fmaxf(aend - alpha0, 0.0f);

      float mid = fmaf(0.5f, dif, alpha0);
      float fx = floorf((fmaf(mid, dx, p0x) + 1.0f) * INV_VOX);
      float fy = floorf((fmaf(mid, dy, p0y) + 1.0f) * INV_VOX);
      float fz = floorf((fmaf(mid, dz, p0z) + 1.0f) * INV_VOX);
      bool inb = (fx >= 0.0f) & (fx < 128.0f) &
                 (fy >= 0.0f) & (fy < 128.0f) &
                 (fz >= 0.0f) & (fz < 128.0f);
      dif = inb ? dif : 0.0f;
      int idx = inb ? (((int)fx << 14) | ((int)fy << 7) | (int)fz) : 0;
      acc = fmaf(dif, __half2float(image[idx]), acc);
    }
    acc *= sqrtf(dx * dx + dy * dy + dz * dz);
  }

  // reduce 64 lane partials
  acc += __shfl_xor(acc, 1);
  acc += __shfl_xor(acc, 2);
  acc += __shfl_xor(acc, 4);
  acc += __shfl_xor(acc, 8);
  acc += __shfl_xor(acc, 16);
  acc += __shfl_xor(acc, 32);
  if (lane == 0) out[ray] = acc;
}

extern "C" void kernel_launch(void* const* d_in, const int* in_sizes, int n_in,
                              void* d_out, int out_size, void* d_ws, size_t ws_size,
                              hipStream_t stream) {
  const float* image = (const float*)d_in[0];   // [128,128,128] f32
  const float* lors  = (const float*)d_in[1];   // [N,6] f32
  float* out = (float*)d_out;                   // [N] f32
  int n = out_size;

  __half* h = (__half*)d_ws;                    // 4 MB fp16 image
  hipLaunchKernelGGL(convert_h, dim3(2048), dim3(256), 0, stream, image, h);

  // one wave (64 lanes) per ray; 4 waves per 256-thread block
  int grid = (n + 3) / 4;
  hipLaunchKernelGGL(siddon_fp, dim3(grid), dim3(256), 0, stream,
                     h, lors, out, n);
}